// Round 10
// baseline (272.179 us; speedup 1.0000x reference)
//
#include <hip/hip_runtime.h>

#define NN  6144
#define ICH 256
#define OCH 128
#define QW  160    // per-row edge cap (Poisson mean 61.4, sd 7.8; 160 = 12+ sigma)

typedef float vf4 __attribute__((ext_vector_type(4)));

// ---------------------------------------------------------------------------
// K1: ft[n][o] = sum_k W[o,k] * x[k,n]  (transposed: per-edge gather reads one
// contiguous 512B row). Epilogue fuses f1/f2 = w1/w2 . ft[n].
// ---------------------------------------------------------------------------
__global__ __launch_bounds__(256) void k_fts(const float* __restrict__ x,
        const float* __restrict__ W, const float* __restrict__ w1,
        const float* __restrict__ w2, float* __restrict__ ft,
        float* __restrict__ f1, float* __restrict__ f2) {
    __shared__ float xs[32][32];        // [kk][nn]
    __shared__ float Ws[32][OCH + 4];   // [kk][o]
    const int n0  = blockIdx.x * 32;
    const int tid = threadIdx.x;
    const int oq = (tid & 31) * 4;      // thread's 4 o's
    const int nq = (tid >> 5) * 4;      // thread's 4 n's
    float acc[4][4] = {};
    for (int k0 = 0; k0 < ICH; k0 += 32) {
        __syncthreads();
        {   // stage x tile: 32k x 32n
            const int nn = tid & 31;
            const int kb = tid >> 5;    // 0..7
#pragma unroll
            for (int r = 0; r < 4; ++r)
                xs[kb + r * 8][nn] = x[(size_t)(k0 + kb + r * 8) * NN + n0 + nn];
        }
        {   // stage W tile: 32k x 128o
            const int kk = tid & 31;
            const int ob = tid >> 5;    // 0..7
#pragma unroll
            for (int r = 0; r < 16; ++r) {
                const int o = ob + r * 8;
                Ws[kk][o] = W[o * ICH + k0 + kk];  // coalesced over k
            }
        }
        __syncthreads();
#pragma unroll
        for (int kk = 0; kk < 32; ++kk) {
            const float4 xv = *(const float4*)&xs[kk][nq];
            const float4 wv = *(const float4*)&Ws[kk][oq];
            const float xa[4] = {xv.x, xv.y, xv.z, xv.w};
            const float wa[4] = {wv.x, wv.y, wv.z, wv.w};
#pragma unroll
            for (int a = 0; a < 4; ++a)
#pragma unroll
                for (int b = 0; b < 4; ++b)
                    acc[a][b] = fmaf(xa[a], wa[b], acc[a][b]);
        }
    }
#pragma unroll
    for (int a = 0; a < 4; ++a) {
        float4 v = make_float4(acc[a][0], acc[a][1], acc[a][2], acc[a][3]);
        *(float4*)&ft[(size_t)(n0 + nq + a) * OCH + oq] = v;
    }
    // ---- fused f1/f2 epilogue: this block holds ALL 128 o for its 32 n ----
    const float4 w1v = *(const float4*)(w1 + oq);
    const float4 w2v = *(const float4*)(w2 + oq);
    float p1[4], p2[4];
#pragma unroll
    for (int a = 0; a < 4; ++a) {
        p1[a] = acc[a][0] * w1v.x + acc[a][1] * w1v.y + acc[a][2] * w1v.z + acc[a][3] * w1v.w;
        p2[a] = acc[a][0] * w2v.x + acc[a][1] * w2v.y + acc[a][2] * w2v.z + acc[a][3] * w2v.w;
    }
#pragma unroll
    for (int m = 16; m > 0; m >>= 1) {
#pragma unroll
        for (int a = 0; a < 4; ++a) {
            p1[a] += __shfl_xor(p1[a], m);
            p2[a] += __shfl_xor(p2[a], m);
        }
    }
    if ((tid & 31) == 0) {
#pragma unroll
        for (int a = 0; a < 4; ++a) {
            f1[n0 + nq + a] = p1[a];
            f2[n0 + nq + a] = p2[a];
        }
    }
}

// ---------------------------------------------------------------------------
// K2 (k_mask_ps): PERSISTENT grid-stride adj->bitmask stream — the m13
// µbench shape: long-lived waves, double-buffered loop, body = compare/pack/
// store only (no LDS, no atomics, no divergence). 512 blocks (2/CU), 2048
// waves; chunk = 2048 floats (8 float4/lane, one u32/lane out). Each XCD
// (blockIdx%8) owns a contiguous 2304-chunk (18.9 MB) region; its 256 waves
// stride-256 through it, 9 chunks each.
// mask layout: word[(i*3+g)*64+lane], bit(k*4+c) <-> j=g*2048+k*256+lane*4+c
// ---------------------------------------------------------------------------
__global__ __launch_bounds__(256) void k_mask_ps(const float* __restrict__ adj,
        unsigned* __restrict__ mask) {
    const int lane = threadIdx.x & 63;
    const int wave = threadIdx.x >> 6;
    const int r = blockIdx.x & 7;              // XCD slot
    const int s = blockIdx.x >> 3;             // 0..63 within XCD
    const int q = s * 4 + wave;                // 0..255: wave index within XCD
    int c = r * 2304 + q;                      // this wave's first chunk
    const float* base0 = adj + (size_t)c * 2048 + lane * 4;
    vf4 buf[2][8];
#pragma unroll
    for (int k = 0; k < 8; ++k)
        buf[0][k] = *(const vf4*)(base0 + k * 256);
#pragma unroll
    for (int t = 0; t < 9; ++t) {
        if (t < 8) {                           // prefetch next chunk (stride 256 chunks)
            const float* pn = adj + ((size_t)c + 256) * 2048 + lane * 4;
#pragma unroll
            for (int k = 0; k < 8; ++k)
                buf[(t + 1) & 1][k] = *(const vf4*)(pn + k * 256);
        }
        unsigned w = 0;
#pragma unroll
        for (int k = 0; k < 8; ++k) {
            const vf4 a4 = buf[t & 1][k];
            w |= (a4.x != 0.f ? 1u : 0u) << (4 * k);
            w |= (a4.y != 0.f ? 2u : 0u) << (4 * k);
            w |= (a4.z != 0.f ? 4u : 0u) << (4 * k);
            w |= (a4.w != 0.f ? 8u : 0u) << (4 * k);
        }
        mask[(size_t)c * 64 + lane] = w;
        c += 256;
    }
}

// ---------------------------------------------------------------------------
// K3 (k_edge): all downstream work — L1/L2-resident (mask 4.7MB, f2 24KB,
// ft 3MB). One wave per row, 4 independent waves/block, no barriers.
// Decode 3 mask words/lane via ballot loop, exp -> LDS queue (ballot-prefix
// slots, no atomics), then half-wave-per-edge float4 ft gathers.
// XCD-affinity row map (same as k_mask_ps regions): out 128B lines dirty
// within one XCD's L2 -> full-line writebacks.
// ---------------------------------------------------------------------------
__global__ __launch_bounds__(256) void k_edge(const unsigned* __restrict__ mask,
        const float* __restrict__ ft, const float* __restrict__ f1,
        const float* __restrict__ f2, const float* __restrict__ b1,
        const float* __restrict__ b2, const float* __restrict__ vb,
        float* __restrict__ out) {
    __shared__ float2 q[4][QW];
    const int tid  = threadIdx.x;
    const int lane = tid & 63;
    const int wave = tid >> 6;
    const int i = (blockIdx.x & 7) * 768 + (blockIdx.x >> 3) * 4 + wave;
    const float s1 = f1[i] + b1[0] + b2[0];
    unsigned mw[3];
#pragma unroll
    for (int g = 0; g < 3; ++g)
        mw[g] = mask[(size_t)(i * 3 + g) * 64 + lane];
    const unsigned long long lt = (1ull << lane) - 1;
    float den = 0.f;
    int cnt = 0;                                   // wave-uniform by construction
#pragma unroll
    for (int g = 0; g < 3; ++g) {
        unsigned w = mw[g];
        for (;;) {                                 // uniform trip count (max bits/lane)
            const unsigned long long act = __ballot(w != 0);
            if (!act) break;
            if (w) {
                const int b = __builtin_ctz(w);
                w &= w - 1;
                const int j = g * 2048 + (b >> 2) * 256 + lane * 4 + (b & 3);
                float s = s1 + f2[j];              // f2: 24KB, L1-resident
                s = s > 0.f ? s : 0.2f * s;
                const float e = __expf(s);
                den += e;
                const int slot = cnt + (int)__popcll(act & lt);
                if (slot < QW)
                    q[wave][slot] = make_float2(__int_as_float(j), e);
            }
            cnt += (int)__popcll(act);
        }
    }
#pragma unroll
    for (int off = 32; off > 0; off >>= 1) den += __shfl_xor(den, off);
    const float inv = 1.f / den;
    const int nE = cnt < QW ? cnt : QW;
    const int half = lane >> 5;
    const int c0 = (lane & 31) * 4;
    float4 nm = make_float4(0.f, 0.f, 0.f, 0.f);
#pragma unroll 4
    for (int idx = half; idx < nE; idx += 2) {     // 2 edges per wave-iter
        const float2 pe = q[wave][idx];            // half-wave LDS broadcast
        const int   j = __float_as_int(pe.x);
        const float e = pe.y;
        const float4 g4 = *(const float4*)(ft + (size_t)j * OCH + c0);
        nm.x = fmaf(e, g4.x, nm.x);
        nm.y = fmaf(e, g4.y, nm.y);
        nm.z = fmaf(e, g4.z, nm.z);
        nm.w = fmaf(e, g4.w, nm.w);
    }
    nm.x += __shfl_xor(nm.x, 32);                  // fold odd-edge half in
    nm.y += __shfl_xor(nm.y, 32);
    nm.z += __shfl_xor(nm.z, 32);
    nm.w += __shfl_xor(nm.w, 32);
    if (half == 0) {
        const float4 bv = *(const float4*)(vb + (size_t)i * OCH + c0);
        // out[0, c, i] = vals[i, c] + vars_bias[0, i, c]
        out[(size_t)(c0    ) * NN + i] = fmaf(nm.x, inv, bv.x);
        out[(size_t)(c0 + 1) * NN + i] = fmaf(nm.y, inv, bv.y);
        out[(size_t)(c0 + 2) * NN + i] = fmaf(nm.z, inv, bv.z);
        out[(size_t)(c0 + 3) * NN + i] = fmaf(nm.w, inv, bv.w);
    }
}

// ---------------------------------------------------------------------------
extern "C" void kernel_launch(void* const* d_in, const int* in_sizes, int n_in,
                              void* d_out, int out_size, void* d_ws, size_t ws_size,
                              hipStream_t stream) {
    const float* x   = (const float*)d_in[0];  // [1,256,6144]
    const float* adj = (const float*)d_in[1];  // [6144,6144]
    const float* W   = (const float*)d_in[2];  // [128,256]
    const float* w1  = (const float*)d_in[3];  // [128]
    const float* b1  = (const float*)d_in[4];  // [1]
    const float* w2  = (const float*)d_in[5];  // [128]
    const float* b2  = (const float*)d_in[6];  // [1]
    const float* vb  = (const float*)d_in[7];  // [1,6144,128]
    float* out = (float*)d_out;                // [1,128,6144]

    char* ws = (char*)d_ws;
    float*    ft   = (float*)ws;                       // 3,145,728 B
    float*    f1   = (float*)(ws + 3145728);           // 24,576 B
    float*    f2   = (float*)(ws + 3145728 + 24576);   // 24,576 B
    unsigned* mask = (unsigned*)(ws + 3194880);        // 18432*64*4 = 4,718,592 B

    k_fts<<<dim3(NN / 32), 256, 0, stream>>>(x, W, w1, w2, ft, f1, f2);
    k_mask_ps<<<dim3(512), 256, 0, stream>>>(adj, mask);
    k_edge<<<dim3(NN / 4), 256, 0, stream>>>(mask, ft, f1, f2, b1, b2, vb, out);
}

// Round 11
// 258.041 us; speedup vs baseline: 1.0548x; 1.0548x over previous
//
#include <hip/hip_runtime.h>

#define NN  6144
#define ICH 256
#define OCH 128
#define QW  160    // per-row edge cap (Poisson mean 61.4, sd 7.8; 160 = 12 sigma)

typedef float vf4 __attribute__((ext_vector_type(4)));

// ---------------------------------------------------------------------------
// K1: ft[n][o] = sum_k W[o,k] * x[k,n]  (transposed: per-edge gather reads one
// contiguous 512B row). Epilogue fuses f1/f2 = w1/w2 . ft[n].
// ---------------------------------------------------------------------------
__global__ __launch_bounds__(256) void k_fts(const float* __restrict__ x,
        const float* __restrict__ W, const float* __restrict__ w1,
        const float* __restrict__ w2, float* __restrict__ ft,
        float* __restrict__ f1, float* __restrict__ f2) {
    __shared__ float xs[32][32];        // [kk][nn]
    __shared__ float Ws[32][OCH + 4];   // [kk][o]
    const int n0  = blockIdx.x * 32;
    const int tid = threadIdx.x;
    const int oq = (tid & 31) * 4;      // thread's 4 o's
    const int nq = (tid >> 5) * 4;      // thread's 4 n's
    float acc[4][4] = {};
    for (int k0 = 0; k0 < ICH; k0 += 32) {
        __syncthreads();
        {   // stage x tile: 32k x 32n
            const int nn = tid & 31;
            const int kb = tid >> 5;    // 0..7
#pragma unroll
            for (int r = 0; r < 4; ++r)
                xs[kb + r * 8][nn] = x[(size_t)(k0 + kb + r * 8) * NN + n0 + nn];
        }
        {   // stage W tile: 32k x 128o
            const int kk = tid & 31;
            const int ob = tid >> 5;    // 0..7
#pragma unroll
            for (int r = 0; r < 16; ++r) {
                const int o = ob + r * 8;
                Ws[kk][o] = W[o * ICH + k0 + kk];  // coalesced over k
            }
        }
        __syncthreads();
#pragma unroll
        for (int kk = 0; kk < 32; ++kk) {
            const float4 xv = *(const float4*)&xs[kk][nq];
            const float4 wv = *(const float4*)&Ws[kk][oq];
            const float xa[4] = {xv.x, xv.y, xv.z, xv.w};
            const float wa[4] = {wv.x, wv.y, wv.z, wv.w};
#pragma unroll
            for (int a = 0; a < 4; ++a)
#pragma unroll
                for (int b = 0; b < 4; ++b)
                    acc[a][b] = fmaf(xa[a], wa[b], acc[a][b]);
        }
    }
#pragma unroll
    for (int a = 0; a < 4; ++a) {
        float4 v = make_float4(acc[a][0], acc[a][1], acc[a][2], acc[a][3]);
        *(float4*)&ft[(size_t)(n0 + nq + a) * OCH + oq] = v;
    }
    // ---- fused f1/f2 epilogue: this block holds ALL 128 o for its 32 n ----
    const float4 w1v = *(const float4*)(w1 + oq);
    const float4 w2v = *(const float4*)(w2 + oq);
    float p1[4], p2[4];
#pragma unroll
    for (int a = 0; a < 4; ++a) {
        p1[a] = acc[a][0] * w1v.x + acc[a][1] * w1v.y + acc[a][2] * w1v.z + acc[a][3] * w1v.w;
        p2[a] = acc[a][0] * w2v.x + acc[a][1] * w2v.y + acc[a][2] * w2v.z + acc[a][3] * w2v.w;
    }
#pragma unroll
    for (int m = 16; m > 0; m >>= 1) {
#pragma unroll
        for (int a = 0; a < 4; ++a) {
            p1[a] += __shfl_xor(p1[a], m);
            p2[a] += __shfl_xor(p2[a], m);
        }
    }
    if ((tid & 31) == 0) {
#pragma unroll
        for (int a = 0; a < 4; ++a) {
            f1[n0 + nq + a] = p1[a];
            f2[n0 + nq + a] = p2[a];
        }
    }
}

// ---------------------------------------------------------------------------
// K2 (k_attn): best-measured structure (R9, 257.2 us total). One wave per
// row, 4 independent waves/block, register double-buffered adj stream,
// per-wave LDS queue, half-wave-per-edge float4 gather.
// XCD-affinity row map: blocks with equal (blockIdx%8) — same XCD under
// round-robin dispatch — own a CONTIGUOUS 768-row range, so each 128B line
// of `out` is dirtied within one XCD's L2 (full-line writeback; kills 5x
// write amplification) and each XCD streams a contiguous 18.9MB adj region.
// NOTE (session evidence): adj read service is capped at ~2.2-2.6 TB/s in
// this environment across 7 structurally distinct consumers (R4-R10);
// kernel shape is exonerated — do not re-litigate with shape changes.
// ---------------------------------------------------------------------------
__global__ __launch_bounds__(256) void k_attn(const float* __restrict__ adj,
        const float* __restrict__ ft, const float* __restrict__ f1,
        const float* __restrict__ f2, const float* __restrict__ b1,
        const float* __restrict__ b2, const float* __restrict__ vb,
        float* __restrict__ out) {
    __shared__ float q_e[4][QW];
    __shared__ int   q_j[4][QW];
    __shared__ int   qc[4];
    const int tid  = threadIdx.x;
    const int lane = tid & 63;
    const int wave = tid >> 6;
    // XCD-affinity remap: r = XCD slot, q = position within its 768-row span
    const int i = (blockIdx.x & 7) * 768 + (blockIdx.x >> 3) * 4 + wave;
    if (lane == 0) qc[wave] = 0;     // same-wave program order: safe w/o barrier
    const float s1 = f1[i] + b1[0] + b2[0];
    const float* arow = adj + (size_t)i * NN;
    float den = 0.f;
    vf4 ab[2][6];
#pragma unroll
    for (int w = 0; w < 6; ++w)
        ab[0][w] = __builtin_nontemporal_load((const vf4*)(arow + lane * 4 + w * 256));
#pragma unroll
    for (int b = 0; b < 4; ++b) {
        if (b < 3) {
#pragma unroll
            for (int w = 0; w < 6; ++w)
                ab[(b + 1) & 1][w] = __builtin_nontemporal_load(
                    (const vf4*)(arow + (b + 1) * 1536 + lane * 4 + w * 256));
        }
#pragma unroll
        for (int w = 0; w < 6; ++w) {
            const vf4 a4 = ab[b & 1][w];
            const int j0 = b * 1536 + w * 256 + lane * 4;
            const int k = (a4.x != 0.f) + (a4.y != 0.f) + (a4.z != 0.f) + (a4.w != 0.f);
            if (k) {                                   // ~4% of lanes
                const float4 g = *(const float4*)(f2 + j0);
                int slot = atomicAdd(&qc[wave], k);    // private counter: no contention
                if (slot + k <= QW) {
                    if (a4.x != 0.f) { float s = s1 + g.x; s = s > 0.f ? s : 0.2f * s;
                                       float e = __expf(s); den += e;
                                       q_j[wave][slot] = j0;     q_e[wave][slot] = e; ++slot; }
                    if (a4.y != 0.f) { float s = s1 + g.y; s = s > 0.f ? s : 0.2f * s;
                                       float e = __expf(s); den += e;
                                       q_j[wave][slot] = j0 + 1; q_e[wave][slot] = e; ++slot; }
                    if (a4.z != 0.f) { float s = s1 + g.z; s = s > 0.f ? s : 0.2f * s;
                                       float e = __expf(s); den += e;
                                       q_j[wave][slot] = j0 + 2; q_e[wave][slot] = e; ++slot; }
                    if (a4.w != 0.f) { float s = s1 + g.w; s = s > 0.f ? s : 0.2f * s;
                                       float e = __expf(s); den += e;
                                       q_j[wave][slot] = j0 + 3; q_e[wave][slot] = e; }
                }
            }
        }
    }
#pragma unroll
    for (int off = 32; off > 0; off >>= 1) den += __shfl_xor(den, off);
    const float inv = 1.f / den;
    const int nE = qc[wave] < QW ? qc[wave] : QW;      // same-wave: ordered after atomics
    const int half = lane >> 5;
    const int c0 = (lane & 31) * 4;
    float4 nm = make_float4(0.f, 0.f, 0.f, 0.f);
#pragma unroll 2
    for (int idx = half; idx < nE; idx += 2) {         // 2 edges/wave-iter
        const int   j = q_j[wave][idx];                // half-wave LDS broadcast
        const float e = q_e[wave][idx];
        const float4 g = *(const float4*)(ft + (size_t)j * OCH + c0);
        nm.x = fmaf(e, g.x, nm.x);
        nm.y = fmaf(e, g.y, nm.y);
        nm.z = fmaf(e, g.z, nm.z);
        nm.w = fmaf(e, g.w, nm.w);
    }
    nm.x += __shfl_xor(nm.x, 32);                      // fold odd-edge half in
    nm.y += __shfl_xor(nm.y, 32);
    nm.z += __shfl_xor(nm.z, 32);
    nm.w += __shfl_xor(nm.w, 32);
    if (half == 0) {
        const float4 bv = *(const float4*)(vb + (size_t)i * OCH + c0);
        // out[0, c, i] = vals[i, c] + vars_bias[0, i, c]
        out[(size_t)(c0    ) * NN + i] = fmaf(nm.x, inv, bv.x);
        out[(size_t)(c0 + 1) * NN + i] = fmaf(nm.y, inv, bv.y);
        out[(size_t)(c0 + 2) * NN + i] = fmaf(nm.z, inv, bv.z);
        out[(size_t)(c0 + 3) * NN + i] = fmaf(nm.w, inv, bv.w);
    }
}

// ---------------------------------------------------------------------------
extern "C" void kernel_launch(void* const* d_in, const int* in_sizes, int n_in,
                              void* d_out, int out_size, void* d_ws, size_t ws_size,
                              hipStream_t stream) {
    const float* x   = (const float*)d_in[0];  // [1,256,6144]
    const float* adj = (const float*)d_in[1];  // [6144,6144]
    const float* W   = (const float*)d_in[2];  // [128,256]
    const float* w1  = (const float*)d_in[3];  // [128]
    const float* b1  = (const float*)d_in[4];  // [1]
    const float* w2  = (const float*)d_in[5];  // [128]
    const float* b2  = (const float*)d_in[6];  // [1]
    const float* vb  = (const float*)d_in[7];  // [1,6144,128]
    float* out = (float*)d_out;                // [1,128,6144]

    char* ws = (char*)d_ws;
    float* ft = (float*)ws;                      // 3,145,728 B
    float* f1 = (float*)(ws + 3145728);          // 24,576 B
    float* f2 = (float*)(ws + 3145728 + 24576);  // 24,576 B

    k_fts<<<dim3(NN / 32), 256, 0, stream>>>(x, W, w1, w2, ft, f1, f2);
    k_attn<<<dim3(NN / 4), 256, 0, stream>>>(adj, ft, f1, f2, b1, b2, vb, out);
}